// Round 8
// baseline (810.320 us; speedup 1.0000x reference)
//
#include <hip/hip_runtime.h>
#include <hip/hip_cooperative_groups.h>

namespace cg = cooperative_groups;

// GCN 3-layer, bf16 datapath:
//   pre (1 cooperative kernel): deg/dinv/CSR build + W->bf16 transpose
//   t' = bf16(dinv_r * (A @ W)) via dbuf MFMA GEMM (f32 accum); A = f32 x (L0) or bf16 h (L1)
//   h  = bf16(relu(dinv_i * (sum_nbr t'[s] + t'[i]) + b))   (bf16 gather, f32 accum)
//   layer2 fused into agg2 (dot W2 in-register) -> z; out = dinv*(sum z[nbr]+z[i]) + b2

static inline size_t alignup(size_t x, size_t a) { return (x + a - 1) & ~(a - 1); }

typedef __attribute__((ext_vector_type(8))) short short8;
typedef __attribute__((ext_vector_type(4))) float f32x4;

__device__ inline unsigned short f2bf(float f) {
    union { float f; unsigned int u; } v; v.f = f;
    unsigned int r = v.u + 0x7FFFu + ((v.u >> 16) & 1u);  // RTNE
    return (unsigned short)(r >> 16);
}
__device__ inline float bf2f(unsigned short u) {
    union { unsigned int u; float f; } v; v.u = ((unsigned int)u) << 16;
    return v.f;
}

// ---------------- cooperative preprocessing ----------------
// Phases separated by grid.sync():
//  P0: deg=0 (N)  ||  Wt0/Wt1 = bf16(W0/W1)^T (2*65536)
//  P1: deg histogram over dst
//  P2: block-local scan of deg -> rs, block sums -> bsum; dinv = rsqrt(deg+1)
//  P3: scan of bsum (block 0)
//  P4: rs += bsum[b]; cursor = rs; rs[N] = E
//  P5: CSR fill via cursor atomics
__global__ __launch_bounds__(256) void k_pre(const int* __restrict__ esrc, const int* __restrict__ edst,
                                             int E, int N,
                                             int* __restrict__ deg, int* __restrict__ rs,
                                             int* __restrict__ cursor, int* __restrict__ col,
                                             int* __restrict__ bsum, float* __restrict__ dinv,
                                             const float* __restrict__ W0, const float* __restrict__ W1,
                                             unsigned short* __restrict__ Wt0, unsigned short* __restrict__ Wt1) {
    cg::grid_group grid = cg::this_grid();
    __shared__ int sd[256];
    int tid = threadIdx.x;
    int b = blockIdx.x;
    int gtid = b * 256 + tid;
    int stride = gridDim.x * 256;
    int nb = (N + 1023) / 1024;

    // P0
    for (int i = gtid; i < N; i += stride) deg[i] = 0;
    for (int i = gtid; i < 131072; i += stride) {
        const float* W = (i < 65536) ? W0 : W1;
        unsigned short* Wt = (i < 65536) ? Wt0 : Wt1;
        int id = i & 65535;
        int k = id >> 8, n = id & 255;
        Wt[(size_t)n * 256 + k] = f2bf(W[(size_t)k * 256 + n]);
    }
    grid.sync();

    // P1
    for (int e = gtid; e < E; e += stride) atomicAdd(&deg[edst[e]], 1);
    grid.sync();

    // P2
    if (b < nb) {
        int base = b * 1024 + tid * 4;
        int v[4];
#pragma unroll
        for (int j = 0; j < 4; ++j) v[j] = (base + j < N) ? deg[base + j] : 0;
        int tot = v[0] + v[1] + v[2] + v[3];
        sd[tid] = tot;
        for (int off = 1; off < 256; off <<= 1) {
            __syncthreads();
            int t = (tid >= off) ? sd[tid - off] : 0;
            __syncthreads();
            sd[tid] += t;
        }
        __syncthreads();
        int run = tid ? sd[tid - 1] : 0;
#pragma unroll
        for (int j = 0; j < 4; ++j) {
            if (base + j < N) {
                rs[base + j] = run;
                dinv[base + j] = rsqrtf((float)v[j] + 1.0f);  // +1 self-loop
            }
            run += v[j];
        }
        if (tid == 255) bsum[b] = sd[255];
    }
    grid.sync();

    // P3
    if (b == 0) {
        sd[tid] = (tid < nb) ? bsum[tid] : 0;
        for (int off = 1; off < 256; off <<= 1) {
            __syncthreads();
            int t = (tid >= off) ? sd[tid - off] : 0;
            __syncthreads();
            sd[tid] += t;
        }
        __syncthreads();
        if (tid < nb) bsum[tid] = tid ? sd[tid - 1] : 0;
    }
    grid.sync();

    // P4
    if (b < nb) {
        int off = bsum[b];
        int base = b * 1024 + tid * 4;
#pragma unroll
        for (int j = 0; j < 4; ++j) {
            int idx = base + j;
            if (idx < N) {
                int v = rs[idx] + off;
                rs[idx] = v;
                cursor[idx] = v;
            }
        }
    }
    if (gtid == 0) rs[N] = E;
    grid.sync();

    // P5
    for (int e = gtid; e < E; e += stride) {
        int d = edst[e];
        int pos = atomicAdd(&cursor[d], 1);
        col[pos] = esrc[e];
    }
}

// ---------------- double-buffered MFMA GEMM ----------------
// C[r][c] = bf16( dinv[r] * sum_k A[r][k]*W[k][c] ); A f32 (AF32) or bf16; Wt bf16 [c][k].
// 128x128 tile, BK=32, 4 waves (2x2). Reg prefetch next k-step; stash to alt LDS buffer;
// ONE barrier per k-step. LDS 32KB total; epilogue Cs aliases both buffers.
// Fragment-major LDS layout: elem(r,k) at ushort idx (r>>4)*512 + (k>>3)*128 + (r&15)*8 + (k&7).
template <bool AF32>
__global__ __launch_bounds__(256) void k_gemm_mfma(const void* __restrict__ Ap,
                                                   const unsigned short* __restrict__ Wt,
                                                   unsigned short* __restrict__ C,
                                                   const float* __restrict__ dinv, int N) {
    __shared__ __align__(16) unsigned short smem[16384];  // 32 KB
    unsigned short* Asb[2] = {smem, smem + 8192};
    unsigned short* Bsb[2] = {smem + 4096, smem + 12288};
    unsigned short* Cs = smem;  // epilogue alias

    int tid = threadIdx.x;
    int lane = tid & 63, w = tid >> 6;
    int wr = w >> 1, wc = w & 1;
    int row0 = blockIdx.y * 128, col0 = blockIdx.x * 128;

    f32x4 acc[4][4];
#pragma unroll
    for (int m = 0; m < 4; ++m)
#pragma unroll
        for (int n = 0; n < 4; ++n) acc[m][n] = (f32x4)0.f;

    const int c0 = tid, c1 = tid + 256;
    const int ar0 = c0 >> 2, akg0 = c0 & 3, ar1 = c1 >> 2, akg1 = c1 & 3;

    auto loadA = [&](int r, int kg, int k0) -> short8 {
        short8 u = {0, 0, 0, 0, 0, 0, 0, 0};
        int grow = row0 + r;
        if (grow < N) {
            if constexpr (AF32) {
                const float* g = (const float*)Ap + (size_t)grow * 256 + k0 + kg * 8;
                float4 f0 = *(const float4*)g;
                float4 f1 = *(const float4*)(g + 4);
                u[0] = (short)f2bf(f0.x); u[1] = (short)f2bf(f0.y);
                u[2] = (short)f2bf(f0.z); u[3] = (short)f2bf(f0.w);
                u[4] = (short)f2bf(f1.x); u[5] = (short)f2bf(f1.y);
                u[6] = (short)f2bf(f1.z); u[7] = (short)f2bf(f1.w);
            } else {
                u = *(const short8*)((const unsigned short*)Ap + (size_t)grow * 256 + k0 + kg * 8);
            }
        }
        return u;
    };
    auto loadB = [&](int n, int kg, int k0) -> short8 {
        return *(const short8*)(Wt + (size_t)(col0 + n) * 256 + k0 + kg * 8);
    };
    auto stash = [&](int buf, short8 a0, short8 a1, short8 b0, short8 b1) {
        *(short8*)&Asb[buf][(ar0 >> 4) * 512 + akg0 * 128 + (ar0 & 15) * 8] = a0;
        *(short8*)&Asb[buf][(ar1 >> 4) * 512 + akg1 * 128 + (ar1 & 15) * 8] = a1;
        *(short8*)&Bsb[buf][(ar0 >> 4) * 512 + akg0 * 128 + (ar0 & 15) * 8] = b0;
        *(short8*)&Bsb[buf][(ar1 >> 4) * 512 + akg1 * 128 + (ar1 & 15) * 8] = b1;
    };

    {
        short8 a0 = loadA(ar0, akg0, 0), a1 = loadA(ar1, akg1, 0);
        short8 b0 = loadB(ar0, akg0, 0), b1 = loadB(ar1, akg1, 0);
        stash(0, a0, a1, b0, b1);
    }
    __syncthreads();

#pragma unroll
    for (int i = 0; i < 8; ++i) {
        int cur = i & 1;
        short8 na0, na1, nb0, nb1;
        if (i < 7) {  // issue next-step global loads early; consumed after MFMA
            int k0 = i * 32 + 32;
            na0 = loadA(ar0, akg0, k0); na1 = loadA(ar1, akg1, k0);
            nb0 = loadB(ar0, akg0, k0); nb1 = loadB(ar1, akg1, k0);
        }
        short8 af[4], bfr[4];
#pragma unroll
        for (int m = 0; m < 4; ++m)
            af[m] = *(const short8*)&Asb[cur][(wr * 4 + m) * 512 + (lane >> 4) * 128 + (lane & 15) * 8];
#pragma unroll
        for (int n = 0; n < 4; ++n)
            bfr[n] = *(const short8*)&Bsb[cur][(wc * 4 + n) * 512 + (lane >> 4) * 128 + (lane & 15) * 8];
#pragma unroll
        for (int m = 0; m < 4; ++m)
#pragma unroll
            for (int n = 0; n < 4; ++n)
                acc[m][n] = __builtin_amdgcn_mfma_f32_16x16x32_bf16(af[m], bfr[n], acc[m][n], 0, 0, 0);
        if (i < 7) stash(cur ^ 1, na0, na1, nb0, nb1);
        __syncthreads();  // one barrier per k-step (dbuf)
    }

    unsigned short* myCs = &Cs[w * 4096];
#pragma unroll
    for (int m = 0; m < 4; ++m) {
#pragma unroll
        for (int j = 0; j < 4; ++j) {
            int r = m * 16 + (lane >> 4) * 4 + j;  // D: row=(l>>4)*4+reg
            int grow = row0 + wr * 64 + r;
            float d = (grow < N) ? dinv[grow] : 0.f;
#pragma unroll
            for (int n = 0; n < 4; ++n)
                myCs[r * 64 + n * 16 + (lane & 15)] = f2bf(acc[m][n][j] * d);  // D: col=l&15
        }
    }
    __syncthreads();
#pragma unroll
    for (int i = 0; i < 8; ++i) {
        int r = i * 8 + (lane >> 3);
        int grow = row0 + wr * 64 + r;
        if (grow < N) {
            short8 v = *(const short8*)&myCs[r * 64 + (lane & 7) * 8];
            *(short8*)(C + (size_t)grow * 256 + col0 + wc * 64 + (lane & 7) * 8) = v;
        }
    }
}

// ---------------- aggregation over bf16 t' ----------------
// one wave per node; lane-halves process even/odd edges; 16B load per lane.
// FUSE_GEMV: also computes z[node] = dinv*dot(relu(h), W2) and skips the h write.
template <bool FUSE_GEMV>
__global__ __launch_bounds__(256) void k_agg(const unsigned short* __restrict__ t,
                                             unsigned short* __restrict__ h,
                                             const int* __restrict__ rs, const int* __restrict__ col,
                                             const float* __restrict__ dinv, const float* __restrict__ bias,
                                             const float* __restrict__ W2, float* __restrict__ z,
                                             int N) {
    int wid = (blockIdx.x * 256 + threadIdx.x) >> 6;
    int lane = threadIdx.x & 63;
    if (wid >= N) return;
    int half = lane >> 5, sub = lane & 31;
    const short8* tp = (const short8*)t;

    short8 sv = tp[(size_t)wid * 32 + sub];
    float hsel = (half == 0) ? 1.f : 0.f;
    float a[8];
#pragma unroll
    for (int i = 0; i < 8; ++i) a[i] = hsel * bf2f((unsigned short)sv[i]);

    int e0 = rs[wid], e1 = rs[wid + 1];
    for (int base = e0; base < e1; base += 64) {
        int m = e1 - base; if (m > 64) m = 64;
        int c = (base + lane < e1) ? col[base + lane] : 0;
        int npairs = (m + 1) >> 1;
        int j = 0;
        for (; j + 4 <= npairs; j += 4) {
            int i0 = 2 * j + half, i1 = i0 + 2, i2 = i0 + 4, i3 = i0 + 6;
            int s0 = __shfl(c, i0), s1 = __shfl(c, i1), s2 = __shfl(c, i2), s3 = __shfl(c, i3);
            float f0 = (i0 < m) ? 1.f : 0.f, f1 = (i1 < m) ? 1.f : 0.f;
            float f2 = (i2 < m) ? 1.f : 0.f, f3 = (i3 < m) ? 1.f : 0.f;
            short8 w0 = tp[(size_t)s0 * 32 + sub];
            short8 w1 = tp[(size_t)s1 * 32 + sub];
            short8 w2 = tp[(size_t)s2 * 32 + sub];
            short8 w3 = tp[(size_t)s3 * 32 + sub];
#pragma unroll
            for (int i = 0; i < 8; ++i) {
                a[i] = fmaf(f0, bf2f((unsigned short)w0[i]), a[i]);
                a[i] = fmaf(f1, bf2f((unsigned short)w1[i]), a[i]);
                a[i] = fmaf(f2, bf2f((unsigned short)w2[i]), a[i]);
                a[i] = fmaf(f3, bf2f((unsigned short)w3[i]), a[i]);
            }
        }
        for (; j < npairs; ++j) {
            int i0 = 2 * j + half;
            int s0 = __shfl(c, i0);
            float f0 = (i0 < m) ? 1.f : 0.f;
            short8 w0 = tp[(size_t)s0 * 32 + sub];
#pragma unroll
            for (int i = 0; i < 8; ++i) a[i] = fmaf(f0, bf2f((unsigned short)w0[i]), a[i]);
        }
    }
#pragma unroll
    for (int i = 0; i < 8; ++i) a[i] += __shfl_xor(a[i], 32, 64);  // both halves hold full sums

    float d = dinv[wid];
    float4 b0 = ((const float4*)bias)[sub * 2];
    float4 b1 = ((const float4*)bias)[sub * 2 + 1];
    float o[8];
    o[0] = fmaf(d, a[0], b0.x); o[1] = fmaf(d, a[1], b0.y);
    o[2] = fmaf(d, a[2], b0.z); o[3] = fmaf(d, a[3], b0.w);
    o[4] = fmaf(d, a[4], b1.x); o[5] = fmaf(d, a[5], b1.y);
    o[6] = fmaf(d, a[6], b1.z); o[7] = fmaf(d, a[7], b1.w);
#pragma unroll
    for (int i = 0; i < 8; ++i) o[i] = fmaxf(o[i], 0.f);  // both layers relu

    if constexpr (FUSE_GEMV) {
        float4 wv0 = ((const float4*)W2)[sub * 2];
        float4 wv1 = ((const float4*)W2)[sub * 2 + 1];
        float zp = o[0] * wv0.x + o[1] * wv0.y + o[2] * wv0.z + o[3] * wv0.w +
                   o[4] * wv1.x + o[5] * wv1.y + o[6] * wv1.z + o[7] * wv1.w;
#pragma unroll
        for (int off = 16; off > 0; off >>= 1) zp += __shfl_down(zp, off, 32);  // within half
        if (lane == 0) z[wid] = d * zp;
    } else {
        if (half == 0) {
            short8 u;
#pragma unroll
            for (int i = 0; i < 8; ++i) u[i] = (short)f2bf(o[i]);
            *(short8*)(h + (size_t)wid * 256 + sub * 8) = u;
        }
    }
}

__global__ __launch_bounds__(256) void k_agg_out(const float* __restrict__ z, float* __restrict__ out,
                                                 const int* __restrict__ rs, const int* __restrict__ col,
                                                 const float* __restrict__ dinv, const float* __restrict__ b2,
                                                 int N) {
    int wid = (blockIdx.x * 256 + threadIdx.x) >> 6;
    int lane = threadIdx.x & 63;
    if (wid >= N) return;
    int e0 = rs[wid], e1 = rs[wid + 1];
    float v = 0.f;
    for (int base = e0; base < e1; base += 64) {
        int e = base + lane;
        if (e < e1) v += z[col[e]];
    }
#pragma unroll
    for (int off = 32; off > 0; off >>= 1) v += __shfl_down(v, off, 64);
    if (lane == 0) out[wid] = fmaf(dinv[wid], v + z[wid], b2[0]);
}

extern "C" void kernel_launch(void* const* d_in, const int* in_sizes, int n_in,
                              void* d_out, int out_size, void* d_ws, size_t ws_size,
                              hipStream_t stream) {
    const float* x  = (const float*)d_in[0];
    const int*   ei = (const int*)d_in[1];
    const float* W0 = (const float*)d_in[2];
    const float* b0 = (const float*)d_in[3];
    const float* W1 = (const float*)d_in[4];
    const float* b1 = (const float*)d_in[5];
    const float* W2 = (const float*)d_in[6];
    const float* b2 = (const float*)d_in[7];
    float* out = (float*)d_out;

    int N = in_sizes[0] / 256;
    int E = in_sizes[1] / 2;
    const int* esrc = ei;
    const int* edst = ei + E;

    char* p = (char*)d_ws;
    unsigned short* tb = (unsigned short*)p; p += alignup((size_t)N * 256 * 2, 16);
    unsigned short* hb = (unsigned short*)p; p += alignup((size_t)N * 256 * 2, 16);
    unsigned short* Wt0 = (unsigned short*)p; p += 256 * 256 * 2;
    unsigned short* Wt1 = (unsigned short*)p; p += 256 * 256 * 2;
    float* z = (float*)p;      p += alignup((size_t)N * 4, 16);
    float* dinv = (float*)p;   p += alignup((size_t)N * 4, 16);
    int* deg = (int*)p;        p += alignup((size_t)N * 4, 16);
    int* cursor = (int*)p;     p += alignup((size_t)N * 4, 16);
    int* rs = (int*)p;         p += alignup((size_t)(N + 1) * 4, 16);
    int* col = (int*)p;        p += alignup((size_t)E * 4, 16);
    int* bsum = (int*)p;       p += 256 * 4;

    dim3 blk(256);

    // cooperative preprocessing: 768 blocks (light kernel, co-resident on 256 CUs)
    {
        void* args[] = {(void*)&esrc, (void*)&edst, (void*)&E, (void*)&N,
                        (void*)&deg, (void*)&rs, (void*)&cursor, (void*)&col,
                        (void*)&bsum, (void*)&dinv,
                        (void*)&W0, (void*)&W1, (void*)&Wt0, (void*)&Wt1};
        hipLaunchCooperativeKernel((const void*)k_pre, dim3(768), blk, args, 0, stream);
    }

    dim3 gg(2, (N + 127) / 128);
    k_gemm_mfma<true><<<gg, blk, 0, stream>>>(x, Wt0, tb, dinv, N);
    k_agg<false><<<(N + 3) / 4, blk, 0, stream>>>(tb, hb, rs, col, dinv, b0, nullptr, nullptr, N);
    k_gemm_mfma<false><<<gg, blk, 0, stream>>>(hb, Wt1, tb, dinv, N);
    k_agg<true><<<(N + 3) / 4, blk, 0, stream>>>(tb, nullptr, rs, col, dinv, b1, W2, z, N);
    k_agg_out<<<(N + 3) / 4, blk, 0, stream>>>(z, out, rs, col, dinv, b2, N);
}

// Round 9
// 370.023 us; speedup vs baseline: 2.1899x; 2.1899x over previous
//
#include <hip/hip_runtime.h>

// GCN 3-layer, bf16 datapath:
//   pre: 7 small kernels (deg/dinv/CSR build + W->bf16 transpose)
//   t' = bf16(dinv_r * (A @ W)) via dbuf MFMA GEMM (f32 accum); A = f32 x (L0) or bf16 h (L1)
//   h  = bf16(relu(dinv_i * (sum_nbr t'[s] + t'[i]) + b))   (bf16 gather, f32 accum)
//   layer2 fused into agg2 (dot W2 in-register) -> z; out = dinv*(sum z[nbr]+z[i]) + b2
// NOTE: cooperative grid.sync() preprocessing measured 523us (~100us/sync) — never again.

static inline size_t alignup(size_t x, size_t a) { return (x + a - 1) & ~(a - 1); }

typedef __attribute__((ext_vector_type(8))) short short8;
typedef __attribute__((ext_vector_type(4))) float f32x4;

__device__ inline unsigned short f2bf(float f) {
    union { float f; unsigned int u; } v; v.f = f;
    unsigned int r = v.u + 0x7FFFu + ((v.u >> 16) & 1u);  // RTNE
    return (unsigned short)(r >> 16);
}
__device__ inline float bf2f(unsigned short u) {
    union { unsigned int u; float f; } v; v.u = ((unsigned int)u) << 16;
    return v.f;
}

// ---------------- preprocessing ----------------
__global__ __launch_bounds__(256) void k_fill_i32(int* __restrict__ p, int v, int n) {
    int i = blockIdx.x * 256 + threadIdx.x;
    if (i < n) p[i] = v;
}

__global__ __launch_bounds__(256) void k_count_deg(const int* __restrict__ dst, int* __restrict__ deg, int E) {
    int e = blockIdx.x * 256 + threadIdx.x;
    if (e < E) atomicAdd(&deg[dst[e]], 1);
}

__global__ __launch_bounds__(256) void k_scan1(const int* __restrict__ deg, int* __restrict__ rs,
                                               int* __restrict__ bsum, float* __restrict__ dinv, int n) {
    __shared__ int sd[256];
    int b = blockIdx.x, tid = threadIdx.x;
    int base = b * 1024 + tid * 4;
    int v[4];
#pragma unroll
    for (int j = 0; j < 4; ++j) v[j] = (base + j < n) ? deg[base + j] : 0;
    int tot = v[0] + v[1] + v[2] + v[3];
    sd[tid] = tot;
    for (int off = 1; off < 256; off <<= 1) {
        __syncthreads();
        int t = (tid >= off) ? sd[tid - off] : 0;
        __syncthreads();
        sd[tid] += t;
    }
    __syncthreads();
    int run = tid ? sd[tid - 1] : 0;
#pragma unroll
    for (int j = 0; j < 4; ++j) {
        if (base + j < n) {
            rs[base + j] = run;
            dinv[base + j] = rsqrtf((float)v[j] + 1.0f);  // +1 self-loop
        }
        run += v[j];
    }
    if (tid == 255) bsum[b] = sd[255];
}

__global__ __launch_bounds__(256) void k_scan2(int* __restrict__ bsum, int nb) {
    __shared__ int sd[256];
    int tid = threadIdx.x;
    sd[tid] = (tid < nb) ? bsum[tid] : 0;
    for (int off = 1; off < 256; off <<= 1) {
        __syncthreads();
        int t = (tid >= off) ? sd[tid - off] : 0;
        __syncthreads();
        sd[tid] += t;
    }
    __syncthreads();
    if (tid < nb) bsum[tid] = tid ? sd[tid - 1] : 0;
}

__global__ __launch_bounds__(256) void k_scan3(int* __restrict__ rs, int* __restrict__ cursor,
                                               const int* __restrict__ bsum, int n, int E) {
    int b = blockIdx.x, tid = threadIdx.x;
    int off = bsum[b];
    int base = b * 1024 + tid * 4;
#pragma unroll
    for (int j = 0; j < 4; ++j) {
        int idx = base + j;
        if (idx < n) {
            int v = rs[idx] + off;
            rs[idx] = v;
            cursor[idx] = v;
        }
    }
    if (b == 0 && tid == 0) rs[n] = E;
}

__global__ __launch_bounds__(256) void k_fill_csr(const int* __restrict__ src, const int* __restrict__ dst,
                                                  int* __restrict__ cursor, int* __restrict__ col, int E) {
    int e = blockIdx.x * 256 + threadIdx.x;
    if (e < E) {
        int d = dst[e];
        int pos = atomicAdd(&cursor[d], 1);
        col[pos] = src[e];
    }
}

__global__ __launch_bounds__(256) void k_wt2(const float* __restrict__ W0, const float* __restrict__ W1,
                                             unsigned short* __restrict__ Wt0, unsigned short* __restrict__ Wt1) {
    int idx = blockIdx.x * 256 + threadIdx.x;  // 0..131071
    const float* W = (idx < 65536) ? W0 : W1;
    unsigned short* Wt = (idx < 65536) ? Wt0 : Wt1;
    int id = idx & 65535;
    int k = id >> 8, n = id & 255;
    Wt[(size_t)n * 256 + k] = f2bf(W[(size_t)k * 256 + n]);
}

// ---------------- double-buffered MFMA GEMM ----------------
// C[r][c] = bf16( dinv[r] * sum_k A[r][k]*W[k][c] ); A f32 (AF32) or bf16; Wt bf16 [c][k].
// 128x128 tile, BK=32, 4 waves (2x2). Reg prefetch next k-step; stash to alt LDS buffer;
// ONE barrier per k-step. LDS 32KB total; epilogue Cs aliases both buffers.
// Fragment-major LDS layout: elem(r,k) at ushort idx (r>>4)*512 + (k>>3)*128 + (r&15)*8 + (k&7).
template <bool AF32>
__global__ __launch_bounds__(256) void k_gemm_mfma(const void* __restrict__ Ap,
                                                   const unsigned short* __restrict__ Wt,
                                                   unsigned short* __restrict__ C,
                                                   const float* __restrict__ dinv, int N) {
    __shared__ __align__(16) unsigned short smem[16384];  // 32 KB
    unsigned short* Asb[2] = {smem, smem + 8192};
    unsigned short* Bsb[2] = {smem + 4096, smem + 12288};
    unsigned short* Cs = smem;  // epilogue alias

    int tid = threadIdx.x;
    int lane = tid & 63, w = tid >> 6;
    int wr = w >> 1, wc = w & 1;
    int row0 = blockIdx.y * 128, col0 = blockIdx.x * 128;

    f32x4 acc[4][4];
#pragma unroll
    for (int m = 0; m < 4; ++m)
#pragma unroll
        for (int n = 0; n < 4; ++n) acc[m][n] = (f32x4)0.f;

    const int c0 = tid, c1 = tid + 256;
    const int ar0 = c0 >> 2, akg0 = c0 & 3, ar1 = c1 >> 2, akg1 = c1 & 3;

    auto loadA = [&](int r, int kg, int k0) -> short8 {
        short8 u = {0, 0, 0, 0, 0, 0, 0, 0};
        int grow = row0 + r;
        if (grow < N) {
            if constexpr (AF32) {
                const float* g = (const float*)Ap + (size_t)grow * 256 + k0 + kg * 8;
                float4 f0 = *(const float4*)g;
                float4 f1 = *(const float4*)(g + 4);
                u[0] = (short)f2bf(f0.x); u[1] = (short)f2bf(f0.y);
                u[2] = (short)f2bf(f0.z); u[3] = (short)f2bf(f0.w);
                u[4] = (short)f2bf(f1.x); u[5] = (short)f2bf(f1.y);
                u[6] = (short)f2bf(f1.z); u[7] = (short)f2bf(f1.w);
            } else {
                u = *(const short8*)((const unsigned short*)Ap + (size_t)grow * 256 + k0 + kg * 8);
            }
        }
        return u;
    };
    auto loadB = [&](int n, int kg, int k0) -> short8 {
        return *(const short8*)(Wt + (size_t)(col0 + n) * 256 + k0 + kg * 8);
    };
    auto stash = [&](int buf, short8 a0, short8 a1, short8 b0, short8 b1) {
        *(short8*)&Asb[buf][(ar0 >> 4) * 512 + akg0 * 128 + (ar0 & 15) * 8] = a0;
        *(short8*)&Asb[buf][(ar1 >> 4) * 512 + akg1 * 128 + (ar1 & 15) * 8] = a1;
        *(short8*)&Bsb[buf][(ar0 >> 4) * 512 + akg0 * 128 + (ar0 & 15) * 8] = b0;
        *(short8*)&Bsb[buf][(ar1 >> 4) * 512 + akg1 * 128 + (ar1 & 15) * 8] = b1;
    };

    {
        short8 a0 = loadA(ar0, akg0, 0), a1 = loadA(ar1, akg1, 0);
        short8 b0 = loadB(ar0, akg0, 0), b1 = loadB(ar1, akg1, 0);
        stash(0, a0, a1, b0, b1);
    }
    __syncthreads();

#pragma unroll
    for (int i = 0; i < 8; ++i) {
        int cur = i & 1;
        short8 na0, na1, nb0, nb1;
        if (i < 7) {  // issue next-step global loads early; consumed after MFMA
            int k0 = i * 32 + 32;
            na0 = loadA(ar0, akg0, k0); na1 = loadA(ar1, akg1, k0);
            nb0 = loadB(ar0, akg0, k0); nb1 = loadB(ar1, akg1, k0);
        }
        short8 af[4], bfr[4];
#pragma unroll
        for (int m = 0; m < 4; ++m)
            af[m] = *(const short8*)&Asb[cur][(wr * 4 + m) * 512 + (lane >> 4) * 128 + (lane & 15) * 8];
#pragma unroll
        for (int n = 0; n < 4; ++n)
            bfr[n] = *(const short8*)&Bsb[cur][(wc * 4 + n) * 512 + (lane >> 4) * 128 + (lane & 15) * 8];
#pragma unroll
        for (int m = 0; m < 4; ++m)
#pragma unroll
            for (int n = 0; n < 4; ++n)
                acc[m][n] = __builtin_amdgcn_mfma_f32_16x16x32_bf16(af[m], bfr[n], acc[m][n], 0, 0, 0);
        if (i < 7) stash(cur ^ 1, na0, na1, nb0, nb1);
        __syncthreads();  // one barrier per k-step (dbuf)
    }

    unsigned short* myCs = &Cs[w * 4096];
#pragma unroll
    for (int m = 0; m < 4; ++m) {
#pragma unroll
        for (int j = 0; j < 4; ++j) {
            int r = m * 16 + (lane >> 4) * 4 + j;  // D: row=(l>>4)*4+reg
            int grow = row0 + wr * 64 + r;
            float d = (grow < N) ? dinv[grow] : 0.f;
#pragma unroll
            for (int n = 0; n < 4; ++n)
                myCs[r * 64 + n * 16 + (lane & 15)] = f2bf(acc[m][n][j] * d);  // D: col=l&15
        }
    }
    __syncthreads();
#pragma unroll
    for (int i = 0; i < 8; ++i) {
        int r = i * 8 + (lane >> 3);
        int grow = row0 + wr * 64 + r;
        if (grow < N) {
            short8 v = *(const short8*)&myCs[r * 64 + (lane & 7) * 8];
            *(short8*)(C + (size_t)grow * 256 + col0 + wc * 64 + (lane & 7) * 8) = v;
        }
    }
}

// ---------------- aggregation over bf16 t' ----------------
// one wave per node; lane-halves process even/odd edges; 16B load per lane.
// FUSE_GEMV: also computes z[node] = dinv*dot(relu(h), W2) and skips the h write.
template <bool FUSE_GEMV>
__global__ __launch_bounds__(256) void k_agg(const unsigned short* __restrict__ t,
                                             unsigned short* __restrict__ h,
                                             const int* __restrict__ rs, const int* __restrict__ col,
                                             const float* __restrict__ dinv, const float* __restrict__ bias,
                                             const float* __restrict__ W2, float* __restrict__ z,
                                             int N) {
    int wid = (blockIdx.x * 256 + threadIdx.x) >> 6;
    int lane = threadIdx.x & 63;
    if (wid >= N) return;
    int half = lane >> 5, sub = lane & 31;
    const short8* tp = (const short8*)t;

    short8 sv = tp[(size_t)wid * 32 + sub];
    float hsel = (half == 0) ? 1.f : 0.f;
    float a[8];
#pragma unroll
    for (int i = 0; i < 8; ++i) a[i] = hsel * bf2f((unsigned short)sv[i]);

    int e0 = rs[wid], e1 = rs[wid + 1];
    for (int base = e0; base < e1; base += 64) {
        int m = e1 - base; if (m > 64) m = 64;
        int c = (base + lane < e1) ? col[base + lane] : 0;
        int npairs = (m + 1) >> 1;
        int j = 0;
        for (; j + 4 <= npairs; j += 4) {
            int i0 = 2 * j + half, i1 = i0 + 2, i2 = i0 + 4, i3 = i0 + 6;
            int s0 = __shfl(c, i0), s1 = __shfl(c, i1), s2 = __shfl(c, i2), s3 = __shfl(c, i3);
            float f0 = (i0 < m) ? 1.f : 0.f, f1 = (i1 < m) ? 1.f : 0.f;
            float f2 = (i2 < m) ? 1.f : 0.f, f3 = (i3 < m) ? 1.f : 0.f;
            short8 w0 = tp[(size_t)s0 * 32 + sub];
            short8 w1 = tp[(size_t)s1 * 32 + sub];
            short8 w2 = tp[(size_t)s2 * 32 + sub];
            short8 w3 = tp[(size_t)s3 * 32 + sub];
#pragma unroll
            for (int i = 0; i < 8; ++i) {
                a[i] = fmaf(f0, bf2f((unsigned short)w0[i]), a[i]);
                a[i] = fmaf(f1, bf2f((unsigned short)w1[i]), a[i]);
                a[i] = fmaf(f2, bf2f((unsigned short)w2[i]), a[i]);
                a[i] = fmaf(f3, bf2f((unsigned short)w3[i]), a[i]);
            }
        }
        for (; j < npairs; ++j) {
            int i0 = 2 * j + half;
            int s0 = __shfl(c, i0);
            float f0 = (i0 < m) ? 1.f : 0.f;
            short8 w0 = tp[(size_t)s0 * 32 + sub];
#pragma unroll
            for (int i = 0; i < 8; ++i) a[i] = fmaf(f0, bf2f((unsigned short)w0[i]), a[i]);
        }
    }
#pragma unroll
    for (int i = 0; i < 8; ++i) a[i] += __shfl_xor(a[i], 32, 64);  // both halves hold full sums

    float d = dinv[wid];
    float4 b0 = ((const float4*)bias)[sub * 2];
    float4 b1 = ((const float4*)bias)[sub * 2 + 1];
    float o[8];
    o[0] = fmaf(d, a[0], b0.x); o[1] = fmaf(d, a[1], b0.y);
    o[2] = fmaf(d, a[2], b0.z); o[3] = fmaf(d, a[3], b0.w);
    o[4] = fmaf(d, a[4], b1.x); o[5] = fmaf(d, a[5], b1.y);
    o[6] = fmaf(d, a[6], b1.z); o[7] = fmaf(d, a[7], b1.w);
#pragma unroll
    for (int i = 0; i < 8; ++i) o[i] = fmaxf(o[i], 0.f);  // both layers relu

    if constexpr (FUSE_GEMV) {
        float4 wv0 = ((const float4*)W2)[sub * 2];
        float4 wv1 = ((const float4*)W2)[sub * 2 + 1];
        float zp = o[0] * wv0.x + o[1] * wv0.y + o[2] * wv0.z + o[3] * wv0.w +
                   o[4] * wv1.x + o[5] * wv1.y + o[6] * wv1.z + o[7] * wv1.w;
#pragma unroll
        for (int off = 16; off > 0; off >>= 1) zp += __shfl_down(zp, off, 32);  // within half
        if (lane == 0) z[wid] = d * zp;
    } else {
        if (half == 0) {
            short8 u;
#pragma unroll
            for (int i = 0; i < 8; ++i) u[i] = (short)f2bf(o[i]);
            *(short8*)(h + (size_t)wid * 256 + sub * 8) = u;
        }
    }
}

__global__ __launch_bounds__(256) void k_agg_out(const float* __restrict__ z, float* __restrict__ out,
                                                 const int* __restrict__ rs, const int* __restrict__ col,
                                                 const float* __restrict__ dinv, const float* __restrict__ b2,
                                                 int N) {
    int wid = (blockIdx.x * 256 + threadIdx.x) >> 6;
    int lane = threadIdx.x & 63;
    if (wid >= N) return;
    int e0 = rs[wid], e1 = rs[wid + 1];
    float v = 0.f;
    for (int base = e0; base < e1; base += 64) {
        int e = base + lane;
        if (e < e1) v += z[col[e]];
    }
#pragma unroll
    for (int off = 32; off > 0; off >>= 1) v += __shfl_down(v, off, 64);
    if (lane == 0) out[wid] = fmaf(dinv[wid], v + z[wid], b2[0]);
}

extern "C" void kernel_launch(void* const* d_in, const int* in_sizes, int n_in,
                              void* d_out, int out_size, void* d_ws, size_t ws_size,
                              hipStream_t stream) {
    const float* x  = (const float*)d_in[0];
    const int*   ei = (const int*)d_in[1];
    const float* W0 = (const float*)d_in[2];
    const float* b0 = (const float*)d_in[3];
    const float* W1 = (const float*)d_in[4];
    const float* b1 = (const float*)d_in[5];
    const float* W2 = (const float*)d_in[6];
    const float* b2 = (const float*)d_in[7];
    float* out = (float*)d_out;

    int N = in_sizes[0] / 256;
    int E = in_sizes[1] / 2;
    const int* esrc = ei;
    const int* edst = ei + E;

    char* p = (char*)d_ws;
    unsigned short* tb = (unsigned short*)p; p += alignup((size_t)N * 256 * 2, 16);
    unsigned short* hb = (unsigned short*)p; p += alignup((size_t)N * 256 * 2, 16);
    unsigned short* Wt0 = (unsigned short*)p; p += 256 * 256 * 2;
    unsigned short* Wt1 = (unsigned short*)p; p += 256 * 256 * 2;
    float* z = (float*)p;      p += alignup((size_t)N * 4, 16);
    float* dinv = (float*)p;   p += alignup((size_t)N * 4, 16);
    int* deg = (int*)p;        p += alignup((size_t)N * 4, 16);
    int* cursor = (int*)p;     p += alignup((size_t)N * 4, 16);
    int* rs = (int*)p;         p += alignup((size_t)(N + 1) * 4, 16);
    int* col = (int*)p;        p += alignup((size_t)E * 4, 16);
    int* bsum = (int*)p;       p += 256 * 4;

    int nb = (N + 1023) / 1024;
    dim3 blk(256);

    k_fill_i32<<<(N + 255) / 256, blk, 0, stream>>>(deg, 0, N);
    k_count_deg<<<(E + 255) / 256, blk, 0, stream>>>(edst, deg, E);
    k_scan1<<<nb, blk, 0, stream>>>(deg, rs, bsum, dinv, N);
    k_scan2<<<1, blk, 0, stream>>>(bsum, nb);
    k_scan3<<<nb, blk, 0, stream>>>(rs, cursor, bsum, N, E);
    k_fill_csr<<<(E + 255) / 256, blk, 0, stream>>>(esrc, edst, cursor, col, E);
    k_wt2<<<512, blk, 0, stream>>>(W0, W1, Wt0, Wt1);

    dim3 gg(2, (N + 127) / 128);
    k_gemm_mfma<true><<<gg, blk, 0, stream>>>(x, Wt0, tb, dinv, N);
    k_agg<false><<<(N + 3) / 4, blk, 0, stream>>>(tb, hb, rs, col, dinv, b0, nullptr, nullptr, N);
    k_gemm_mfma<false><<<gg, blk, 0, stream>>>(hb, Wt1, tb, dinv, N);
    k_agg<true><<<(N + 3) / 4, blk, 0, stream>>>(tb, nullptr, rs, col, dinv, b1, W2, z, N);
    k_agg_out<<<(N + 3) / 4, blk, 0, stream>>>(z, out, rs, col, dinv, b2, N);
}

// Round 10
// 363.957 us; speedup vs baseline: 2.2264x; 1.0167x over previous
//
#include <hip/hip_runtime.h>

// GCN 3-layer, bf16 datapath:
//   pre: 5 kernels (init+wt | count | scan1 | scan3(inline bsum scan) | fill_csr)
//   t' = bf16(dinv_r * (A @ W)) via MFMA GEMM: A dbuf in LDS, B fragments direct
//        from global (W is 128KB bf16 -> L2-resident across all 782 blocks)
//   h  = bf16(relu(dinv_i * (sum_nbr t'[s] + t'[i]) + b))   (bf16 gather, f32 accum)
//   layer2 fused into agg2 (dot W2 in-register) -> z; out = dinv*(sum z[nbr]+z[i]) + b2
// NOTE: cooperative grid.sync() preprocessing measured 523us (~100us/sync) — never again.
// NOTE: agg is a measured wall: ~58us, FETCH=7.2x buffer (full cross-XCD L3 replication
//       of the 25.6MB t' under random gather) — identical across 4 implementations.

static inline size_t alignup(size_t x, size_t a) { return (x + a - 1) & ~(a - 1); }

typedef __attribute__((ext_vector_type(8))) short short8;
typedef __attribute__((ext_vector_type(4))) float f32x4;

__device__ inline unsigned short f2bf(float f) {
    union { float f; unsigned int u; } v; v.f = f;
    unsigned int r = v.u + 0x7FFFu + ((v.u >> 16) & 1u);  // RTNE
    return (unsigned short)(r >> 16);
}
__device__ inline float bf2f(unsigned short u) {
    union { unsigned int u; float f; } v; v.u = ((unsigned int)u) << 16;
    return v.f;
}

// ---------------- preprocessing ----------------
// blocks [0, nbN): deg = 0.  blocks [nbN, nbN+512): W0/W1 -> bf16 transposed.
__global__ __launch_bounds__(256) void k_init(int* __restrict__ deg, int n, int nbN,
                                              const float* __restrict__ W0, const float* __restrict__ W1,
                                              unsigned short* __restrict__ Wt0,
                                              unsigned short* __restrict__ Wt1) {
    int b = blockIdx.x;
    if (b < nbN) {
        int i = b * 256 + threadIdx.x;
        if (i < n) deg[i] = 0;
    } else {
        int idx = (b - nbN) * 256 + threadIdx.x;  // 0..131071
        const float* W = (idx < 65536) ? W0 : W1;
        unsigned short* Wt = (idx < 65536) ? Wt0 : Wt1;
        int id = idx & 65535;
        int k = id >> 8, nn = id & 255;
        Wt[(size_t)nn * 256 + k] = f2bf(W[(size_t)k * 256 + nn]);
    }
}

__global__ __launch_bounds__(256) void k_count_deg(const int* __restrict__ dst, int* __restrict__ deg, int E) {
    int e = blockIdx.x * 256 + threadIdx.x;
    if (e < E) atomicAdd(&deg[dst[e]], 1);
}

__global__ __launch_bounds__(256) void k_scan1(const int* __restrict__ deg, int* __restrict__ rs,
                                               int* __restrict__ bsum, float* __restrict__ dinv, int n) {
    __shared__ int sd[256];
    int b = blockIdx.x, tid = threadIdx.x;
    int base = b * 1024 + tid * 4;
    int v[4];
#pragma unroll
    for (int j = 0; j < 4; ++j) v[j] = (base + j < n) ? deg[base + j] : 0;
    int tot = v[0] + v[1] + v[2] + v[3];
    sd[tid] = tot;
    for (int off = 1; off < 256; off <<= 1) {
        __syncthreads();
        int t = (tid >= off) ? sd[tid - off] : 0;
        __syncthreads();
        sd[tid] += t;
    }
    __syncthreads();
    int run = tid ? sd[tid - 1] : 0;
#pragma unroll
    for (int j = 0; j < 4; ++j) {
        if (base + j < n) {
            rs[base + j] = run;
            dinv[base + j] = rsqrtf((float)v[j] + 1.0f);  // +1 self-loop
        }
        run += v[j];
    }
    if (tid == 255) bsum[b] = sd[255];  // raw per-block total
}

// scan of bsum done redundantly per block (nb<=256), then apply + cursor init.
__global__ __launch_bounds__(256) void k_scan3(int* __restrict__ rs, int* __restrict__ cursor,
                                               const int* __restrict__ bsum, int nb, int n, int E) {
    __shared__ int sd[256];
    int b = blockIdx.x, tid = threadIdx.x;
    sd[tid] = (tid < nb) ? bsum[tid] : 0;
    for (int off = 1; off < 256; off <<= 1) {
        __syncthreads();
        int t = (tid >= off) ? sd[tid - off] : 0;
        __syncthreads();
        sd[tid] += t;
    }
    __syncthreads();
    int off = b ? sd[b - 1] : 0;  // exclusive offset for this block
    int base = b * 1024 + tid * 4;
#pragma unroll
    for (int j = 0; j < 4; ++j) {
        int idx = base + j;
        if (idx < n) {
            int v = rs[idx] + off;
            rs[idx] = v;
            cursor[idx] = v;
        }
    }
    if (b == 0 && tid == 0) rs[n] = E;
}

__global__ __launch_bounds__(256) void k_fill_csr(const int* __restrict__ src, const int* __restrict__ dst,
                                                  int* __restrict__ cursor, int* __restrict__ col, int E) {
    int e = blockIdx.x * 256 + threadIdx.x;
    if (e < E) {
        int d = dst[e];
        int pos = atomicAdd(&cursor[d], 1);
        col[pos] = src[e];
    }
}

// ---------------- MFMA GEMM: A-dbuf LDS, B direct-from-L2 registers ----------------
// C[r][c] = bf16( dinv[r] * sum_k A[r][k]*W[k][c] ); A f32 (AF32) or bf16; Wt bf16 [c][k].
// 128x128 tile, BK=32, 4 waves (2x2). Per k-step: issue A(k+1)->regs and B(k+1)->regs,
// MFMA k from LDS A-frags + reg B-frags, stash A, ONE barrier.
// A LDS fragment layout: elem(r,k) at ushort idx (r>>4)*512 + (k>>3)*128 + (r&15)*8 + (k&7).
template <bool AF32>
__global__ __launch_bounds__(256) void k_gemm_mfma(const void* __restrict__ Ap,
                                                   const unsigned short* __restrict__ Wt,
                                                   unsigned short* __restrict__ C,
                                                   const float* __restrict__ dinv, int N) {
    __shared__ __align__(16) unsigned short smem[16384];  // 32 KB
    unsigned short* Asb[2] = {smem, smem + 4096};         // 8KB each
    unsigned short* Cs = smem;                            // epilogue alias (32KB)

    int tid = threadIdx.x;
    int lane = tid & 63, w = tid >> 6;
    int wr = w >> 1, wc = w & 1;
    int row0 = blockIdx.y * 128, col0 = blockIdx.x * 128;

    f32x4 acc[4][4];
#pragma unroll
    for (int m = 0; m < 4; ++m)
#pragma unroll
        for (int n = 0; n < 4; ++n) acc[m][n] = (f32x4)0.f;

    const int ar = tid >> 1, akg = (tid & 1) << 1;  // A tile: 128 rows x 32k; thread: 2x short8 (16 k)
    // B fragment global base: col = col0 + wc*64 + n*16 + (lane&15); k = k0 + (lane>>4)*8
    const unsigned short* Bbase = Wt + (size_t)(col0 + wc * 64 + (lane & 15)) * 256 + (lane >> 4) * 8;

    auto loadA2 = [&](int k0, short8& u0, short8& u1) {
        u0 = (short8){0, 0, 0, 0, 0, 0, 0, 0}; u1 = u0;
        int grow = row0 + ar;
        if (grow < N) {
            if constexpr (AF32) {
                const float* g = (const float*)Ap + (size_t)grow * 256 + k0 + akg * 8;
                float4 f0 = *(const float4*)g;
                float4 f1 = *(const float4*)(g + 4);
                float4 f2 = *(const float4*)(g + 8);
                float4 f3 = *(const float4*)(g + 12);
                u0[0] = (short)f2bf(f0.x); u0[1] = (short)f2bf(f0.y);
                u0[2] = (short)f2bf(f0.z); u0[3] = (short)f2bf(f0.w);
                u0[4] = (short)f2bf(f1.x); u0[5] = (short)f2bf(f1.y);
                u0[6] = (short)f2bf(f1.z); u0[7] = (short)f2bf(f1.w);
                u1[0] = (short)f2bf(f2.x); u1[1] = (short)f2bf(f2.y);
                u1[2] = (short)f2bf(f2.z); u1[3] = (short)f2bf(f2.w);
                u1[4] = (short)f2bf(f3.x); u1[5] = (short)f2bf(f3.y);
                u1[6] = (short)f2bf(f3.z); u1[7] = (short)f2bf(f3.w);
            } else {
                const unsigned short* g = (const unsigned short*)Ap + (size_t)grow * 256 + k0 + akg * 8;
                u0 = *(const short8*)g;
                u1 = *(const short8*)(g + 8);
            }
        }
    };
    auto stashA = [&](int buf, short8 u0, short8 u1) {
        *(short8*)&Asb[buf][(ar >> 4) * 512 + akg * 128 + (ar & 15) * 8] = u0;
        *(short8*)&Asb[buf][(ar >> 4) * 512 + (akg + 1) * 128 + (ar & 15) * 8] = u1;
    };
    auto loadBfrags = [&](int k0, short8* bf) {
#pragma unroll
        for (int n = 0; n < 4; ++n)
            bf[n] = *(const short8*)(Bbase + (size_t)(n * 16) * 256 + k0);
    };

    short8 bcur[4], bnext[4];
    {
        short8 a0, a1;
        loadA2(0, a0, a1);
        stashA(0, a0, a1);
        loadBfrags(0, bcur);
    }
    __syncthreads();

#pragma unroll
    for (int i = 0; i < 8; ++i) {
        int cur = i & 1;
        short8 na0, na1;
        if (i < 7) {
            loadA2(i * 32 + 32, na0, na1);
            loadBfrags(i * 32 + 32, bnext);
        }
        short8 af[4];
#pragma unroll
        for (int m = 0; m < 4; ++m)
            af[m] = *(const short8*)&Asb[cur][(wr * 4 + m) * 512 + (lane >> 4) * 128 + (lane & 15) * 8];
#pragma unroll
        for (int m = 0; m < 4; ++m)
#pragma unroll
            for (int n = 0; n < 4; ++n)
                acc[m][n] = __builtin_amdgcn_mfma_f32_16x16x32_bf16(af[m], bcur[n], acc[m][n], 0, 0, 0);
        if (i < 7) {
            stashA(cur ^ 1, na0, na1);
#pragma unroll
            for (int n = 0; n < 4; ++n) bcur[n] = bnext[n];
        }
        __syncthreads();
    }

    unsigned short* myCs = &Cs[w * 4096];
#pragma unroll
    for (int m = 0; m < 4; ++m) {
#pragma unroll
        for (int j = 0; j < 4; ++j) {
            int r = m * 16 + (lane >> 4) * 4 + j;  // D: row=(l>>4)*4+reg
            int grow = row0 + wr * 64 + r;
            float d = (grow < N) ? dinv[grow] : 0.f;
#pragma unroll
            for (int n = 0; n < 4; ++n)
                myCs[r * 64 + n * 16 + (lane & 15)] = f2bf(acc[m][n][j] * d);  // D: col=l&15
        }
    }
    __syncthreads();
#pragma unroll
    for (int i = 0; i < 8; ++i) {
        int r = i * 8 + (lane >> 3);
        int grow = row0 + wr * 64 + r;
        if (grow < N) {
            short8 v = *(const short8*)&myCs[r * 64 + (lane & 7) * 8];
            *(short8*)(C + (size_t)grow * 256 + col0 + wc * 64 + (lane & 7) * 8) = v;
        }
    }
}

// ---------------- aggregation over bf16 t' ----------------
template <bool FUSE_GEMV>
__global__ __launch_bounds__(256) void k_agg(const unsigned short* __restrict__ t,
                                             unsigned short* __restrict__ h,
                                             const int* __restrict__ rs, const int* __restrict__ col,
                                             const float* __restrict__ dinv, const float* __restrict__ bias,
                                             const float* __restrict__ W2, float* __restrict__ z,
                                             int N) {
    int wid = (blockIdx.x * 256 + threadIdx.x) >> 6;
    int lane = threadIdx.x & 63;
    if (wid >= N) return;
    int half = lane >> 5, sub = lane & 31;
    const short8* tp = (const short8*)t;

    short8 sv = tp[(size_t)wid * 32 + sub];
    float hsel = (half == 0) ? 1.f : 0.f;
    float a[8];
#pragma unroll
    for (int i = 0; i < 8; ++i) a[i] = hsel * bf2f((unsigned short)sv[i]);

    int e0 = rs[wid], e1 = rs[wid + 1];
    for (int base = e0; base < e1; base += 64) {
        int m = e1 - base; if (m > 64) m = 64;
        int c = (base + lane < e1) ? col[base + lane] : 0;
        int npairs = (m + 1) >> 1;
        int j = 0;
        for (; j + 4 <= npairs; j += 4) {
            int i0 = 2 * j + half, i1 = i0 + 2, i2 = i0 + 4, i3 = i0 + 6;
            int s0 = __shfl(c, i0), s1 = __shfl(c, i1), s2 = __shfl(c, i2), s3 = __shfl(c, i3);
            float f0 = (i0 < m) ? 1.f : 0.f, f1 = (i1 < m) ? 1.f : 0.f;
            float f2 = (i2 < m) ? 1.f : 0.f, f3 = (i3 < m) ? 1.f : 0.f;
            short8 w0 = tp[(size_t)s0 * 32 + sub];
            short8 w1 = tp[(size_t)s1 * 32 + sub];
            short8 w2 = tp[(size_t)s2 * 32 + sub];
            short8 w3 = tp[(size_t)s3 * 32 + sub];
#pragma unroll
            for (int i = 0; i < 8; ++i) {
                a[i] = fmaf(f0, bf2f((unsigned short)w0[i]), a[i]);
                a[i] = fmaf(f1, bf2f((unsigned short)w1[i]), a[i]);
                a[i] = fmaf(f2, bf2f((unsigned short)w2[i]), a[i]);
                a[i] = fmaf(f3, bf2f((unsigned short)w3[i]), a[i]);
            }
        }
        for (; j < npairs; ++j) {
            int i0 = 2 * j + half;
            int s0 = __shfl(c, i0);
            float f0 = (i0 < m) ? 1.f : 0.f;
            short8 w0 = tp[(size_t)s0 * 32 + sub];
#pragma unroll
            for (int i = 0; i < 8; ++i) a[i] = fmaf(f0, bf2f((unsigned short)w0[i]), a[i]);
        }
    }
#pragma unroll
    for (int i = 0; i < 8; ++i) a[i] += __shfl_xor(a[i], 32, 64);

    float d = dinv[wid];
    float4 b0 = ((const float4*)bias)[sub * 2];
    float4 b1 = ((const float4*)bias)[sub * 2 + 1];
    float o[8];
    o[0] = fmaf(d, a[0], b0.x); o[1] = fmaf(d, a[1], b0.y);
    o[2] = fmaf(d, a[2], b0.z); o[3] = fmaf(d, a[3], b0.w);
    o[4] = fmaf(d, a[4], b1.x); o[5] = fmaf(d, a[5], b1.y);
    o[6] = fmaf(d, a[6], b1.z); o[7] = fmaf(d, a[7], b1.w);
#pragma unroll
    for (int i = 0; i < 8; ++i) o[i] = fmaxf(o[i], 0.f);  // both layers relu

    if constexpr (FUSE_GEMV) {
        float4 wv0 = ((const float4*)W2)[sub * 2];
        float4 wv1 = ((const float4*)W2)[sub * 2 + 1];
        float zp = o[0] * wv0.x + o[1] * wv0.y + o[2] * wv0.z + o[3] * wv0.w +
                   o[4] * wv1.x + o[5] * wv1.y + o[6] * wv1.z + o[7] * wv1.w;
#pragma unroll
        for (int off = 16; off > 0; off >>= 1) zp += __shfl_down(zp, off, 32);
        if (lane == 0) z[wid] = d * zp;
    } else {
        if (half == 0) {
            short8 u;
#pragma unroll
            for (int i = 0; i < 8; ++i) u[i] = (short)f2bf(o[i]);
            *(short8*)(h + (size_t)wid * 256 + sub * 8) = u;
        }
    }
}

__global__ __launch_bounds__(256) void k_agg_out(const float* __restrict__ z, float* __restrict__ out,
                                                 const int* __restrict__ rs, const int* __restrict__ col,
                                                 const float* __restrict__ dinv, const float* __restrict__ b2,
                                                 int N) {
    int wid = (blockIdx.x * 256 + threadIdx.x) >> 6;
    int lane = threadIdx.x & 63;
    if (wid >= N) return;
    int e0 = rs[wid], e1 = rs[wid + 1];
    float v = 0.f;
    for (int base = e0; base < e1; base += 64) {
        int e = base + lane;
        if (e < e1) v += z[col[e]];
    }
#pragma unroll
    for (int off = 32; off > 0; off >>= 1) v += __shfl_down(v, off, 64);
    if (lane == 0) out[wid] = fmaf(dinv[wid], v + z[wid], b2[0]);
}

extern "C" void kernel_launch(void* const* d_in, const int* in_sizes, int n_in,
                              void* d_out, int out_size, void* d_ws, size_t ws_size,
                              hipStream_t stream) {
    const float* x  = (const float*)d_in[0];
    const int*   ei = (const int*)d_in[1];
    const float* W0 = (const float*)d_in[2];
    const float* b0 = (const float*)d_in[3];
    const float* W1 = (const float*)d_in[4];
    const float* b1 = (const float*)d_in[5];
    const float* W2 = (const float*)d_in[6];
    const float* b2 = (const float*)d_in[7];
    float* out = (float*)d_out;

    int N = in_sizes[0] / 256;
    int E = in_sizes[1] / 2;
    const int* esrc = ei;
    const int* edst = ei + E;

    char* p = (char*)d_ws;
    unsigned short* tb = (unsigned short*)p; p += alignup((size_t)N * 256 * 2, 16);
    unsigned short* hb = (unsigned short*)p; p += alignup((size_t)N * 256 * 2, 16);
    unsigned short* Wt0 = (unsigned short*)p; p += 256 * 256 * 2;
    unsigned short* Wt1 = (unsigned short*)p; p += 256 * 256 * 2;
    float* z = (float*)p;      p += alignup((size_t)N * 4, 16);
    float* dinv = (float*)p;   p += alignup((size_t)N * 4, 16);
    int* deg = (int*)p;        p += alignup((size_t)N * 4, 16);
    int* cursor = (int*)p;     p += alignup((size_t)N * 4, 16);
    int* rs = (int*)p;         p += alignup((size_t)(N + 1) * 4, 16);
    int* col = (int*)p;        p += alignup((size_t)E * 4, 16);
    int* bsum = (int*)p;       p += 256 * 4;

    int nb = (N + 1023) / 1024;     // 49
    int nbN = (N + 255) / 256;      // 196
    dim3 blk(256);

    k_init<<<nbN + 512, blk, 0, stream>>>(deg, N, nbN, W0, W1, Wt0, Wt1);
    k_count_deg<<<(E + 255) / 256, blk, 0, stream>>>(edst, deg, E);
    k_scan1<<<nb, blk, 0, stream>>>(deg, rs, bsum, dinv, N);
    k_scan3<<<nb, blk, 0, stream>>>(rs, cursor, bsum, nb, N, E);
    k_fill_csr<<<(E + 255) / 256, blk, 0, stream>>>(esrc, edst, cursor, col, E);

    dim3 gg(2, (N + 127) / 128);
    k_gemm_mfma<true><<<gg, blk, 0, stream>>>(x, Wt0, tb, dinv, N);
    k_agg<false><<<(N + 3) / 4, blk, 0, stream>>>(tb, hb, rs, col, dinv, b0, nullptr, nullptr, N);
    k_gemm_mfma<false><<<gg, blk, 0, stream>>>(hb, Wt1, tb, dinv, N);
    k_agg<true><<<(N + 3) / 4, blk, 0, stream>>>(tb, nullptr, rs, col, dinv, b1, W2, z, N);
    k_agg_out<<<(N + 3) / 4, blk, 0, stream>>>(z, out, rs, col, dinv, b2, N);
}